// Round 5
// baseline (2201.833 us; speedup 1.0000x reference)
//
#include <hip/hip_runtime.h>
#include <cstddef>

namespace {

constexpr int T = 128;

typedef unsigned short u16;
typedef unsigned int u32;
typedef unsigned long long u64;
typedef __attribute__((ext_vector_type(8))) short short8;
typedef __attribute__((ext_vector_type(4))) float f32x4;

__device__ __forceinline__ u16 f2bf(float x) {
  u32 u = __float_as_uint(x);
  u = (u + 0x7FFFu + ((u >> 16) & 1u)) >> 16;
  return (u16)u;
}
__device__ __forceinline__ float bf2f(u16 v) {
  return __uint_as_float(((u32)v) << 16);
}
__device__ __forceinline__ float sigf(float x) {
  x = fminf(fmaxf(x, -30.f), 30.f);
  return 1.f / (1.f + __expf(-x));
}
__device__ __forceinline__ float tanhfast(float x) {
  float ax = fminf(fabsf(x), 15.f);
  float e = __expf(-2.f * ax);
  float t = (1.f - e) / (1.f + e);
  return x < 0.f ? -t : t;
}

// ---- WBF sub-offsets (ushort units) ----
constexpr int O_WIH = 0;            // 2*2048*512
constexpr int O_AW1 = 2097152;      // 512*512
constexpr int O_EM1 = 2359296;      // 128*128
constexpr int O_EM2 = 2375680;      // 64*128
constexpr int O_MLP = 2383872;      // 64*512
constexpr int O_LW1 = 2416640;      // 256*128
constexpr int O_LW2 = 2449408;      // 128*256
constexpr int O_LW3 = 2482176;      // 64*128
constexpr int N_WBF = 2490368;

// ---------------------------------------------------------------------------
// One-time fp32 -> bf16 weight conversion into workspace
// ---------------------------------------------------------------------------
__global__ __launch_bounds__(256)
void k_prep(const float* __restrict__ wih, const float* __restrict__ aw1,
            const float* __restrict__ e1, const float* __restrict__ e2,
            const float* __restrict__ mw, const float* __restrict__ l1,
            const float* __restrict__ l2, const float* __restrict__ l3,
            u16* __restrict__ wbf) {
  int i = blockIdx.x * 256 + threadIdx.x;
  if (i >= N_WBF) return;
  float v;
  if (i < O_AW1)      v = wih[i];
  else if (i < O_EM1) v = aw1[i - O_AW1];
  else if (i < O_EM2) v = e1[i - O_EM1];
  else if (i < O_MLP) v = e2[i - O_EM2];
  else if (i < O_LW1) v = mw[i - O_MLP];
  else if (i < O_LW2) v = l1[i - O_LW1];
  else if (i < O_LW3) v = l2[i - O_LW2];
  else                v = l3[i - O_LW3];
  wbf[i] = f2bf(v);
}

// ---------------------------------------------------------------------------
// xg = X @ Wih_l^T + bih + bhh   via MFMA.  grid (256 rowblk, 8 nchunk)
// ---------------------------------------------------------------------------
__global__ __launch_bounds__(256)
void k_xg_mfma(const float* __restrict__ X, const u16* __restrict__ Wbf,
               const float* __restrict__ bi, const float* __restrict__ bh,
               float* __restrict__ xg) {
  __shared__ __align__(16) u16 sx[32 * 520];
  int tid = threadIdx.x;
  int rowbase = blockIdx.x * 32;
  int nchunk = blockIdx.y;
  for (int idx = tid; idx < 4096; idx += 256) {
    int r = idx >> 7, k4 = idx & 127;
    float4 v = *(const float4*)(X + (size_t)(rowbase + r) * 512 + k4 * 4);
    u32* p = (u32*)(sx + r * 520 + k4 * 4);
    p[0] = (u32)f2bf(v.x) | ((u32)f2bf(v.y) << 16);
    p[1] = (u32)f2bf(v.z) | ((u32)f2bf(v.w) << 16);
  }
  __syncthreads();
  int w = tid >> 6, lane = tid & 63;
  int msub = w >> 1, nhalf = w & 1;
  int mbase = msub * 16;
  int nb0 = nchunk * 256 + nhalf * 128;
  f32x4 acc[8];
#pragma unroll
  for (int i = 0; i < 8; ++i) acc[i] = f32x4{0.f, 0.f, 0.f, 0.f};
  for (int kt = 0; kt < 16; ++kt) {
    short8 a = *(const short8*)(sx + (mbase + (lane & 15)) * 520 + kt * 32 + (lane >> 4) * 8);
#pragma unroll
    for (int nt = 0; nt < 8; ++nt) {
      short8 b = *(const short8*)(Wbf + (size_t)(nb0 + nt * 16 + (lane & 15)) * 512 +
                                  kt * 32 + (lane >> 4) * 8);
      acc[nt] = __builtin_amdgcn_mfma_f32_16x16x32_bf16(a, b, acc[nt], 0, 0, 0);
    }
  }
  int mr = mbase + (lane >> 4) * 4;
#pragma unroll
  for (int nt = 0; nt < 8; ++nt) {
    int n = nb0 + nt * 16 + (lane & 15);
    float bb = bi[n] + bh[n];
#pragma unroll
    for (int r = 0; r < 4; ++r)
      xg[(size_t)(rowbase + mr + r) * 2048 + n] = acc[nt][r] + bb;
  }
}

// ---------------------------------------------------------------------------
// MFMA LSTM v3: 32 blocks = [d:2][j-chunk c:16]. Barrier-free exchange:
// each h bf16-pair is published as ONE u64 atomic {tag:32 | bf16x2:32} in
// parity ping-pong buffers. Consumers poll exactly the 32 tagged words their
// MFMA A-fragments need (bulk-issued loads, selective re-load of stale).
// No __syncthreads, no flags, no store-ack waits anywhere in the loop.
// ---------------------------------------------------------------------------
__global__ __launch_bounds__(256, 1)
void k_lstm3(const float* __restrict__ xg, const float* __restrict__ whh,
             const int* __restrict__ lens, float* __restrict__ out,
             u64* __restrict__ th, int layer) {
  const int d = blockIdx.x >> 4, c = blockIdx.x & 15;
  const int tid = threadIdx.x;
  const int l = tid & 63;
  const int w = tid >> 6;
  const int ln = l & 15, lk = l >> 4;

  // B fragments: gate rows g*256 + c*16 + ln, k = kk*32 + lk*8 .. +8
  short8 Bf[8][4];
  const float* wbase = whh + (size_t)(layer * 2 + d) * 262144;
#pragma unroll
  for (int kk = 0; kk < 8; ++kk) {
#pragma unroll
    for (int g = 0; g < 4; ++g) {
      const float* rp = wbase + (size_t)(g * 256 + c * 16 + ln) * 256 + kk * 32 + lk * 8;
      float4 lo = *(const float4*)rp;
      float4 hi = *(const float4*)(rp + 4);
      short8 b;
      b[0] = (short)f2bf(lo.x); b[1] = (short)f2bf(lo.y);
      b[2] = (short)f2bf(lo.z); b[3] = (short)f2bf(lo.w);
      b[4] = (short)f2bf(hi.x); b[5] = (short)f2bf(hi.y);
      b[6] = (short)f2bf(hi.z); b[7] = (short)f2bf(hi.w);
      Bf[kk][g] = b;
    }
  }

  const int m0 = w * 16;                // wave's batch tile base
  const int j  = c * 16 + ln;           // this lane's hidden col
  int mlen[4];
#pragma unroll
  for (int r = 0; r < 4; ++r) mlen[r] = lens[m0 + lk * 4 + r];

  float cst[4], hst[4];
#pragma unroll
  for (int r = 0; r < 4; ++r) { cst[r] = 0.f; hst[r] = 0.f; }

  // prefetch xv for s = 0
  float xv[4][4];
  {
    int t0 = d ? 127 : 0;
#pragma unroll
    for (int g = 0; g < 4; ++g)
#pragma unroll
      for (int r = 0; r < 4; ++r)
        xv[g][r] = xg[((size_t)(m0 + lk * 4 + r) * 128 + t0) * 2048 + d * 1024 + g * 256 + j];
  }

  for (int s = 0; s < 128; ++s) {
    const int t = d ? (127 - s) : s;

    f32x4 acc[4];
#pragma unroll
    for (int g = 0; g < 4; ++g) acc[g] = f32x4{0.f, 0.f, 0.f, 0.f};

    if (s > 0) {
      const u32 want = (u32)(layer * 128 + s);           // tag of step s-1
      const u64* hb = th + ((size_t)(d * 2 + ((s - 1) & 1)) * 64 + m0 + ln) * 128;
      u64 v[8][4];
#pragma unroll
      for (int kk = 0; kk < 8; ++kk)
#pragma unroll
        for (int q = 0; q < 4; ++q)
          v[kk][q] = __hip_atomic_load(hb + kk * 16 + lk * 4 + q,
                                       __ATOMIC_RELAXED, __HIP_MEMORY_SCOPE_AGENT);
      for (;;) {
        bool ok = true;
#pragma unroll
        for (int kk = 0; kk < 8; ++kk)
#pragma unroll
          for (int q = 0; q < 4; ++q) ok &= ((u32)(v[kk][q] >> 32) == want);
        if (__all(ok)) break;
#pragma unroll
        for (int kk = 0; kk < 8; ++kk)
#pragma unroll
          for (int q = 0; q < 4; ++q)
            if ((u32)(v[kk][q] >> 32) != want)
              v[kk][q] = __hip_atomic_load(hb + kk * 16 + lk * 4 + q,
                                           __ATOMIC_RELAXED, __HIP_MEMORY_SCOPE_AGENT);
      }
#pragma unroll
      for (int kk = 0; kk < 8; ++kk) {
        short8 a;
#pragma unroll
        for (int q = 0; q < 4; ++q) {
          u32 dw = (u32)v[kk][q];
          a[2 * q]     = (short)(dw & 0xFFFFu);
          a[2 * q + 1] = (short)(dw >> 16);
        }
#pragma unroll
        for (int g = 0; g < 4; ++g)
          acc[g] = __builtin_amdgcn_mfma_f32_16x16x32_bf16(a, Bf[kk][g], acc[g], 0, 0, 0);
      }
    }

    // ---- gates + state update; publish h_s as tagged u64s (no waits) ----
    const u64 wtag = (u64)(u32)(layer * 128 + s + 1) << 32;
    u64* thw = th + (size_t)(d * 2 + (s & 1)) * 8192;    // [64 m][128 jp]
#pragma unroll
    for (int r = 0; r < 4; ++r) {
      float gi = acc[0][r] + xv[0][r];
      float gf = acc[1][r] + xv[1][r];
      float gg = acc[2][r] + xv[2][r];
      float go = acc[3][r] + xv[3][r];
      float c2 = sigf(gf) * cst[r] + sigf(gi) * tanhfast(gg);
      float h2 = sigf(go) * tanhfast(c2);
      const int m = m0 + lk * 4 + r;
      bool upd = t < mlen[r];
      cst[r] = upd ? c2 : cst[r];
      float hn = upd ? h2 : hst[r];
      hst[r] = hn;
      u16 myv = f2bf(hn);
      u16 other = (u16)__shfl_xor((int)myv, 1);
      if ((ln & 1) == 0) {
        u64 val = wtag | (u64)((u32)myv | ((u32)other << 16));
        __hip_atomic_store(thw + m * 128 + c * 8 + (ln >> 1), val,
                           __ATOMIC_RELAXED, __HIP_MEMORY_SCOPE_AGENT);
      }
      out[((size_t)m * 128 + t) * 512 + d * 256 + j] = hn;
    }

    // prefetch xv for next step; flies during next poll
    if (s < 127) {
      const int tn = d ? (127 - (s + 1)) : (s + 1);
#pragma unroll
      for (int g = 0; g < 4; ++g)
#pragma unroll
        for (int r = 0; r < 4; ++r)
          xv[g][r] = xg[((size_t)(m0 + lk * 4 + r) * 128 + tn) * 2048 + d * 1024 + g * 256 + j];
    }
  }
}

// ---------------------------------------------------------------------------
// attn scores via MFMA: sc[m] = w2 . tanh(W1 @ rnn[m] + b1)
// ---------------------------------------------------------------------------
__global__ __launch_bounds__(256)
void k_attn(const float* __restrict__ rnn, const u16* __restrict__ W1bf,
            const float* __restrict__ b1, const float* __restrict__ w2,
            float* __restrict__ sc) {
  __shared__ __align__(16) u16 sx[32 * 520];
  __shared__ float sred[32];
  int tid = threadIdx.x;
  int rowbase = blockIdx.x * 32;
  for (int idx = tid; idx < 4096; idx += 256) {
    int r = idx >> 7, k4 = idx & 127;
    float4 v = *(const float4*)(rnn + (size_t)(rowbase + r) * 512 + k4 * 4);
    u32* p = (u32*)(sx + r * 520 + k4 * 4);
    p[0] = (u32)f2bf(v.x) | ((u32)f2bf(v.y) << 16);
    p[1] = (u32)f2bf(v.z) | ((u32)f2bf(v.w) << 16);
  }
  if (tid < 32) sred[tid] = 0.f;
  __syncthreads();
  int w = tid >> 6, lane = tid & 63;
  int msub = w >> 1, nhalf = w & 1;
  int mbase = msub * 16;
  float psum[4] = {0.f, 0.f, 0.f, 0.f};
  for (int ng = 0; ng < 4; ++ng) {
    f32x4 acc[4];
#pragma unroll
    for (int i = 0; i < 4; ++i) acc[i] = f32x4{0.f, 0.f, 0.f, 0.f};
    for (int kt = 0; kt < 16; ++kt) {
      short8 a = *(const short8*)(sx + (mbase + (lane & 15)) * 520 + kt * 32 + (lane >> 4) * 8);
#pragma unroll
      for (int nt = 0; nt < 4; ++nt) {
        int nrow = nhalf * 256 + ng * 64 + nt * 16 + (lane & 15);
        short8 b = *(const short8*)(W1bf + (size_t)nrow * 512 + kt * 32 + (lane >> 4) * 8);
        acc[nt] = __builtin_amdgcn_mfma_f32_16x16x32_bf16(a, b, acc[nt], 0, 0, 0);
      }
    }
#pragma unroll
    for (int nt = 0; nt < 4; ++nt) {
      int n = nhalf * 256 + ng * 64 + nt * 16 + (lane & 15);
      float wn = w2[n], bn = b1[n];
#pragma unroll
      for (int r = 0; r < 4; ++r) psum[r] += wn * tanhf(acc[nt][r] + bn);
    }
  }
#pragma unroll
  for (int off = 8; off >= 1; off >>= 1)
#pragma unroll
    for (int r = 0; r < 4; ++r) psum[r] += __shfl_xor(psum[r], off);
  if ((lane & 15) == 0) {
#pragma unroll
    for (int r = 0; r < 4; ++r)
      atomicAdd(&sred[msub * 16 + (lane >> 4) * 4 + r], psum[r]);
  }
  __syncthreads();
  if (tid < 32) sc[rowbase + tid] = sred[tid];
}

// ---------------------------------------------------------------------------
// Causal softmax + weighted sum as prefix scan. grid (64 b, 4 hchunk) x 128.
// ---------------------------------------------------------------------------
__global__ __launch_bounds__(128)
void k_ctx(const float* __restrict__ sc, const float* __restrict__ rnn,
           const int* __restrict__ lens, float* __restrict__ ctx) {
  int b = blockIdx.x;
  int h = blockIdx.y * 128 + threadIdx.x;
  __shared__ float ex[T];
  ex[threadIdx.x] = expf(sc[b * T + threadIdx.x]);
  __syncthreads();
  int len = lens[b];
  float acc = 0.f, den = 0.f;
  for (int t = 0; t < T; ++t) {
    float wv = ex[t];
    den += wv;
    acc += wv * rnn[((size_t)b * T + t) * 512 + h];
    ctx[((size_t)b * T + t) * 512 + h] = (t < len) ? (acc / den) : 0.f;
  }
}

// ---------------------------------------------------------------------------
// MFMA MLP stage on a 32-row bf16 LDS tile
// ---------------------------------------------------------------------------
template <int NT, int KT, bool RELU>
__device__ __forceinline__ void stage_mfma(const u16* __restrict__ Wbf,
                                           const float* __restrict__ bias,
                                           const u16* A, int lda,
                                           u16* O, int ldo, int nofs,
                                           int lane, int msub, int nhalf) {
  f32x4 acc[NT];
#pragma unroll
  for (int i = 0; i < NT; ++i) acc[i] = f32x4{0.f, 0.f, 0.f, 0.f};
  int mbase = msub * 16;
  int nb0 = nhalf * (NT * 16);
#pragma unroll
  for (int kt = 0; kt < KT; ++kt) {
    short8 a = *(const short8*)(A + (mbase + (lane & 15)) * lda + kt * 32 + (lane >> 4) * 8);
#pragma unroll
    for (int nt = 0; nt < NT; ++nt) {
      short8 b = *(const short8*)(Wbf + (size_t)(nb0 + nt * 16 + (lane & 15)) * (KT * 32) +
                                  kt * 32 + (lane >> 4) * 8);
      acc[nt] = __builtin_amdgcn_mfma_f32_16x16x32_bf16(a, b, acc[nt], 0, 0, 0);
    }
  }
  int mr = mbase + (lane >> 4) * 4;
#pragma unroll
  for (int nt = 0; nt < NT; ++nt) {
    int nl = nb0 + nt * 16 + (lane & 15);
    float bv = bias[nl];
#pragma unroll
    for (int r = 0; r < 4; ++r) {
      float v = acc[nt][r] + bv;
      if (RELU) v = fmaxf(v, 0.f);
      O[(mr + r) * ldo + nofs + nl] = f2bf(v);
    }
  }
}

// ---------------------------------------------------------------------------
// Fused sample branch, MFMA everywhere. 32 rows/block, 4096 blocks.
// ---------------------------------------------------------------------------
__global__ __launch_bounds__(256)
void k_sample(const float* __restrict__ ctx, const float* __restrict__ d2v,
              const float* __restrict__ user_table, const float* __restrict__ art_table,
              const int* __restrict__ user_ids, const int* __restrict__ sample_ids,
              const u16* __restrict__ wbf,
              const float* __restrict__ em_b1, const float* __restrict__ em_b2,
              const float* __restrict__ mlp_b,
              const float* __restrict__ lm_b1, const float* __restrict__ lm_b2,
              const float* __restrict__ lm_b3,
              const float* __restrict__ lm_W4, const float* __restrict__ lm_b4,
              float* __restrict__ out) {
  __shared__ __align__(16) u16 bufA[32 * 520];
  __shared__ __align__(16) u16 bufB[32 * 264];
  __shared__ __align__(16) u16 bufC[32 * 136];
  int tid = threadIdx.x, lane = tid & 63, w = tid >> 6;
  int msub = w >> 1, nhalf = w & 1;
  int rowbase = blockIdx.x * 32;

  for (int idx = tid; idx < 1024; idx += 256) {
    int r = idx >> 5, k4 = idx & 31;
    int m = rowbase + r;
    int sid = sample_ids[m];
    int uid = user_ids[m >> 11];
    float4 u = *(const float4*)(user_table + (size_t)uid * 128 + k4 * 4);
    float4 a = *(const float4*)(art_table + (size_t)sid * 128 + k4 * 4);
    u32* p = (u32*)(bufA + r * 520 + k4 * 4);
    p[0] = (u32)f2bf(u.x * a.x) | ((u32)f2bf(u.y * a.y) << 16);
    p[1] = (u32)f2bf(u.z * a.z) | ((u32)f2bf(u.w * a.w) << 16);
  }
  __syncthreads();
  stage_mfma<4, 4, true>(wbf + O_EM1, em_b1, bufA, 520, bufB, 264, 0, lane, msub, nhalf);
  __syncthreads();
  stage_mfma<2, 4, true>(wbf + O_EM2, em_b2, bufB, 264, bufC, 136, 0, lane, msub, nhalf);
  for (int idx = tid; idx < 4096; idx += 256) {
    int r = idx >> 7, k4 = idx & 127;
    int m = rowbase + r;
    int bt = m >> 4;
    float4 cx = *(const float4*)(ctx + (size_t)bt * 512 + k4 * 4);
    float4 dv = *(const float4*)(d2v + (size_t)m * 512 + k4 * 4);
    u32* p = (u32*)(bufA + r * 520 + k4 * 4);
    p[0] = (u32)f2bf(cx.x * dv.x) | ((u32)f2bf(cx.y * dv.y) << 16);
    p[1] = (u32)f2bf(cx.z * dv.z) | ((u32)f2bf(cx.w * dv.w) << 16);
  }
  __syncthreads();
  stage_mfma<2, 16, false>(wbf + O_MLP, mlp_b, bufA, 520, bufC, 136, 64, lane, msub, nhalf);
  __syncthreads();
  stage_mfma<8, 4, true>(wbf + O_LW1, lm_b1, bufC, 136, bufB, 264, 0, lane, msub, nhalf);
  __syncthreads();
  stage_mfma<4, 8, true>(wbf + O_LW2, lm_b2, bufB, 264, bufA, 520, 0, lane, msub, nhalf);
  __syncthreads();
  stage_mfma<2, 4, true>(wbf + O_LW3, lm_b3, bufA, 520, bufC, 136, 0, lane, msub, nhalf);
  __syncthreads();

  if (tid < 32) {
    float acc = lm_b4[0];
#pragma unroll
    for (int k = 0; k < 64; ++k) acc += bf2f(bufC[tid * 136 + k]) * lm_W4[k];
    out[rowbase + tid] = 1.f / (1.f + expf(-acc));
  }
}

}  // namespace

extern "C" void kernel_launch(void* const* d_in, const int* in_sizes, int n_in,
                              void* d_out, int out_size, void* d_ws, size_t ws_size,
                              hipStream_t stream) {
  const float* x1   = (const float*)d_in[0];
  const float* d2v  = (const float*)d_in[1];
  const float* Wih  = (const float*)d_in[2];
  const float* Whh  = (const float*)d_in[3];
  const float* bih  = (const float*)d_in[4];
  const float* bhh  = (const float*)d_in[5];
  const float* aW1  = (const float*)d_in[6];
  const float* ab1  = (const float*)d_in[7];
  const float* aw2  = (const float*)d_in[8];
  const float* mlpW = (const float*)d_in[9];
  const float* mlpb = (const float*)d_in[10];
  const float* utab = (const float*)d_in[11];
  const float* atab = (const float*)d_in[12];
  const float* emW1 = (const float*)d_in[13];
  const float* emb1 = (const float*)d_in[14];
  const float* emW2 = (const float*)d_in[15];
  const float* emb2 = (const float*)d_in[16];
  const float* lmW1 = (const float*)d_in[17];
  const float* lmb1 = (const float*)d_in[18];
  const float* lmW2 = (const float*)d_in[19];
  const float* lmb2 = (const float*)d_in[20];
  const float* lmW3 = (const float*)d_in[21];
  const float* lmb3 = (const float*)d_in[22];
  const float* lmW4 = (const float*)d_in[23];
  const float* lmb4 = (const float*)d_in[24];
  const int* lens   = (const int*)d_in[27];
  const int* uids   = (const int*)d_in[28];
  const int* sids   = (const int*)d_in[29];
  float* out = (float*)d_out;

  float* ws = (float*)d_ws;
  // float-unit offsets
  u64* TH  = (u64*)ws;                                 // 32768 u64 [0, 65536)
  float* SC  = ws + 65536;                             // 8192
  u16* WBF = (u16*)(ws + 73728);                       // 2,490,368 u16
  float* XG  = ws + 1318912;                           // 16,777,216
  float* R0  = ws + 18096128;                          // 4,194,304
  float* R1  = ws + 22290432;                          // 4,194,304
  float* CTX = ws + 26484736;                          // 4,194,304

  hipMemsetAsync(TH, 0, 262144, stream);
  k_prep<<<(N_WBF + 255) / 256, 256, 0, stream>>>(Wih, aW1, emW1, emW2, mlpW,
                                                  lmW1, lmW2, lmW3, WBF);
  k_xg_mfma<<<dim3(256, 8), 256, 0, stream>>>(x1, WBF + O_WIH, bih, bhh, XG);
  k_lstm3<<<32, 256, 0, stream>>>(XG, Whh, lens, R0, TH, 0);
  k_xg_mfma<<<dim3(256, 8), 256, 0, stream>>>(R0, WBF + O_WIH + 1048576,
                                              bih + 2048, bhh + 2048, XG);
  k_lstm3<<<32, 256, 0, stream>>>(XG, Whh, lens, R1, TH, 1);
  k_attn<<<256, 256, 0, stream>>>(R1, WBF + O_AW1, ab1, aw2, SC);
  k_ctx<<<dim3(64, 4), 128, 0, stream>>>(SC, R1, lens, CTX);
  k_sample<<<4096, 256, 0, stream>>>(CTX, d2v, utab, atab, uids, sids, WBF,
                                     emb1, emb2, mlpb, lmb1, lmb2, lmb3,
                                     lmW4, lmb4, out);
}

// Round 6
// 1793.178 us; speedup vs baseline: 1.2279x; 1.2279x over previous
//
#include <hip/hip_runtime.h>
#include <cstddef>

namespace {

constexpr int T = 128;

typedef unsigned short u16;
typedef unsigned int u32;
typedef unsigned long long u64;
typedef __attribute__((ext_vector_type(8))) short short8;
typedef __attribute__((ext_vector_type(4))) float f32x4;

__device__ __forceinline__ u16 f2bf(float x) {
  u32 u = __float_as_uint(x);
  u = (u + 0x7FFFu + ((u >> 16) & 1u)) >> 16;
  return (u16)u;
}
__device__ __forceinline__ float bf2f(u16 v) {
  return __uint_as_float(((u32)v) << 16);
}
__device__ __forceinline__ float sigf(float x) {
  x = fminf(fmaxf(x, -30.f), 30.f);
  return 1.f / (1.f + __expf(-x));
}
__device__ __forceinline__ float tanhfast(float x) {
  float ax = fminf(fabsf(x), 15.f);
  float e = __expf(-2.f * ax);
  float t = (1.f - e) / (1.f + e);
  return x < 0.f ? -t : t;
}

// ---- WBF sub-offsets (ushort units) ----
constexpr int O_WIH = 0;            // 2*2048*512
constexpr int O_AW1 = 2097152;      // 512*512
constexpr int O_EM1 = 2359296;      // 128*128
constexpr int O_EM2 = 2375680;      // 64*128
constexpr int O_MLP = 2383872;      // 64*512
constexpr int O_LW1 = 2416640;      // 256*128
constexpr int O_LW2 = 2449408;      // 128*256
constexpr int O_LW3 = 2482176;      // 64*128
constexpr int N_WBF = 2490368;

// ---------------------------------------------------------------------------
// One-time fp32 -> bf16 weight conversion into workspace
// ---------------------------------------------------------------------------
__global__ __launch_bounds__(256)
void k_prep(const float* __restrict__ wih, const float* __restrict__ aw1,
            const float* __restrict__ e1, const float* __restrict__ e2,
            const float* __restrict__ mw, const float* __restrict__ l1,
            const float* __restrict__ l2, const float* __restrict__ l3,
            u16* __restrict__ wbf) {
  int i = blockIdx.x * 256 + threadIdx.x;
  if (i >= N_WBF) return;
  float v;
  if (i < O_AW1)      v = wih[i];
  else if (i < O_EM1) v = aw1[i - O_AW1];
  else if (i < O_EM2) v = e1[i - O_EM1];
  else if (i < O_MLP) v = e2[i - O_EM2];
  else if (i < O_LW1) v = mw[i - O_MLP];
  else if (i < O_LW2) v = l1[i - O_LW1];
  else if (i < O_LW3) v = l2[i - O_LW2];
  else                v = l3[i - O_LW3];
  wbf[i] = f2bf(v);
}

// ---------------------------------------------------------------------------
// xg = X @ Wih_l^T + bih + bhh   via MFMA.  grid (256 rowblk, 8 nchunk)
// ---------------------------------------------------------------------------
__global__ __launch_bounds__(256)
void k_xg_mfma(const float* __restrict__ X, const u16* __restrict__ Wbf,
               const float* __restrict__ bi, const float* __restrict__ bh,
               float* __restrict__ xg) {
  __shared__ __align__(16) u16 sx[32 * 520];
  int tid = threadIdx.x;
  int rowbase = blockIdx.x * 32;
  int nchunk = blockIdx.y;
  for (int idx = tid; idx < 4096; idx += 256) {
    int r = idx >> 7, k4 = idx & 127;
    float4 v = *(const float4*)(X + (size_t)(rowbase + r) * 512 + k4 * 4);
    u32* p = (u32*)(sx + r * 520 + k4 * 4);
    p[0] = (u32)f2bf(v.x) | ((u32)f2bf(v.y) << 16);
    p[1] = (u32)f2bf(v.z) | ((u32)f2bf(v.w) << 16);
  }
  __syncthreads();
  int w = tid >> 6, lane = tid & 63;
  int msub = w >> 1, nhalf = w & 1;
  int mbase = msub * 16;
  int nb0 = nchunk * 256 + nhalf * 128;
  f32x4 acc[8];
#pragma unroll
  for (int i = 0; i < 8; ++i) acc[i] = f32x4{0.f, 0.f, 0.f, 0.f};
  for (int kt = 0; kt < 16; ++kt) {
    short8 a = *(const short8*)(sx + (mbase + (lane & 15)) * 520 + kt * 32 + (lane >> 4) * 8);
#pragma unroll
    for (int nt = 0; nt < 8; ++nt) {
      short8 b = *(const short8*)(Wbf + (size_t)(nb0 + nt * 16 + (lane & 15)) * 512 +
                                  kt * 32 + (lane >> 4) * 8);
      acc[nt] = __builtin_amdgcn_mfma_f32_16x16x32_bf16(a, b, acc[nt], 0, 0, 0);
    }
  }
  int mr = mbase + (lane >> 4) * 4;
#pragma unroll
  for (int nt = 0; nt < 8; ++nt) {
    int n = nb0 + nt * 16 + (lane & 15);
    float bb = bi[n] + bh[n];
#pragma unroll
    for (int r = 0; r < 4; ++r)
      xg[(size_t)(rowbase + mr + r) * 2048 + n] = acc[nt][r] + bb;
  }
}

// ---------------------------------------------------------------------------
// MFMA LSTM v4: 32 blocks = [d:2][j-chunk c:16]. Per-WAVE monotonic flags
// (64 per direction, 1 per lane to poll). Per-step wave protocol:
//   h-stores -> s_waitcnt vmcnt(0) -> flag -> out[]-stores -> xv prefetch
// so HBM out-writes and xg loads drain in the shadow of the next poll.
// No __syncthreads in the loop. h via agent-scope atomics, parity ping-pong.
// Safety: flag>=s implies that wave finished READING parity (s-2), so
// overwriting parity s&1 at step s is race-free (per-wave induction).
// ---------------------------------------------------------------------------
__global__ __launch_bounds__(256, 1)
void k_lstm4(const float* __restrict__ xg, const float* __restrict__ whh,
             const int* __restrict__ lens, float* __restrict__ out,
             u16* __restrict__ hg, u32* __restrict__ flg, int layer) {
  const int d = blockIdx.x >> 4, c = blockIdx.x & 15;
  const int tid = threadIdx.x;
  const int l = tid & 63;
  const int w = tid >> 6;
  const int ln = l & 15, lk = l >> 4;

  // B fragments: gate rows g*256 + c*16 + ln, k = kk*32 + lk*8 .. +8
  short8 Bf[8][4];
  const float* wbase = whh + (size_t)(layer * 2 + d) * 262144;
#pragma unroll
  for (int kk = 0; kk < 8; ++kk) {
#pragma unroll
    for (int g = 0; g < 4; ++g) {
      const float* rp = wbase + (size_t)(g * 256 + c * 16 + ln) * 256 + kk * 32 + lk * 8;
      float4 lo = *(const float4*)rp;
      float4 hi = *(const float4*)(rp + 4);
      short8 b;
      b[0] = (short)f2bf(lo.x); b[1] = (short)f2bf(lo.y);
      b[2] = (short)f2bf(lo.z); b[3] = (short)f2bf(lo.w);
      b[4] = (short)f2bf(hi.x); b[5] = (short)f2bf(hi.y);
      b[6] = (short)f2bf(hi.z); b[7] = (short)f2bf(hi.w);
      Bf[kk][g] = b;
    }
  }

  u16* hbuf0 = hg + d * 32768;          // parity 0: [64 m][256 j] bf16
  u16* hbuf1 = hbuf0 + 16384;           // parity 1
  u32* fbase = flg + d * 64;            // 64 wave-flags, monotonic step count
  const int myflag = c * 4 + w;

  const int m0 = w * 16;                // wave's batch tile base
  const int j  = c * 16 + ln;           // this lane's hidden col
  int mlen[4];
#pragma unroll
  for (int r = 0; r < 4; ++r) mlen[r] = lens[m0 + lk * 4 + r];

  float cst[4], hst[4];
#pragma unroll
  for (int r = 0; r < 4; ++r) { cst[r] = 0.f; hst[r] = 0.f; }

  // prefetch xv for s = 0
  float xv[4][4];
  {
    int t0 = d ? 127 : 0;
#pragma unroll
    for (int g = 0; g < 4; ++g)
#pragma unroll
      for (int r = 0; r < 4; ++r)
        xv[g][r] = xg[((size_t)(m0 + lk * 4 + r) * 128 + t0) * 2048 + d * 1024 + g * 256 + j];
  }

  for (int s = 0; s < 128; ++s) {
    const int t = d ? (127 - s) : s;

    // accumulator initialized with xg pre-activations (C-in of first MFMA)
    f32x4 acc[4];
#pragma unroll
    for (int g = 0; g < 4; ++g)
      acc[g] = f32x4{xv[g][0], xv[g][1], xv[g][2], xv[g][3]};

    if (s > 0) {
      // ---- poll the 64 producer wave-flags (one per lane, single load) ----
      const u32 tgt = (u32)(layer * 128 + s);
      for (;;) {
        u32 fv = __hip_atomic_load(fbase + l, __ATOMIC_RELAXED, __HIP_MEMORY_SCOPE_AGENT);
        if (__all(fv >= tgt)) break;
        __builtin_amdgcn_s_sleep(1);
      }
      // ---- A fragments: h_{s-1} from parity (s-1)&1 ----
      const u16* hp = ((s - 1) & 1) ? hbuf1 : hbuf0;
#pragma unroll
      for (int kk = 0; kk < 8; ++kk) {
        const u64* p = (const u64*)(hp + (m0 + ln) * 256 + kk * 32 + lk * 8);
        union { u64 q[2]; short8 v; } ua;
        ua.q[0] = __hip_atomic_load(p, __ATOMIC_RELAXED, __HIP_MEMORY_SCOPE_AGENT);
        ua.q[1] = __hip_atomic_load(p + 1, __ATOMIC_RELAXED, __HIP_MEMORY_SCOPE_AGENT);
        short8 a = ua.v;
#pragma unroll
        for (int g = 0; g < 4; ++g)
          acc[g] = __builtin_amdgcn_mfma_f32_16x16x32_bf16(a, Bf[kk][g], acc[g], 0, 0, 0);
      }
    }

    // ---- gates + state update; publish h_s (parity s&1) ----
    u16* hw = (s & 1) ? hbuf1 : hbuf0;
    float hnv[4];
#pragma unroll
    for (int r = 0; r < 4; ++r) {
      float gi = acc[0][r];
      float gf = acc[1][r];
      float gg = acc[2][r];
      float go = acc[3][r];
      float c2 = sigf(gf) * cst[r] + sigf(gi) * tanhfast(gg);
      float h2 = sigf(go) * tanhfast(c2);
      const int m = m0 + lk * 4 + r;
      bool upd = t < mlen[r];
      cst[r] = upd ? c2 : cst[r];
      float hn = upd ? h2 : hst[r];
      hst[r] = hn;
      hnv[r] = hn;
      u16 myv = f2bf(hn);
      u16 other = (u16)__shfl_xor((int)myv, 1);
      if ((ln & 1) == 0) {
        u32 word = (u32)myv | ((u32)other << 16);
        __hip_atomic_store((u32*)(hw + m * 256 + (j & ~1)), word,
                           __ATOMIC_RELAXED, __HIP_MEMORY_SCOPE_AGENT);
      }
    }

    // drain ONLY the just-issued h stores (out/xv from prev step long done)
    asm volatile("s_waitcnt vmcnt(0)" ::: "memory");

    if (s < 127)
      __hip_atomic_store(fbase + myflag, (u32)(layer * 128 + s + 1),
                         __ATOMIC_RELAXED, __HIP_MEMORY_SCOPE_AGENT);

    // out[] writes AFTER flag: drain in the shadow of the next poll
#pragma unroll
    for (int r = 0; r < 4; ++r) {
      const int m = m0 + lk * 4 + r;
      out[((size_t)m * 128 + t) * 512 + d * 256 + j] = hnv[r];
    }

    // xv prefetch for next step; flies during next poll
    if (s < 127) {
      const int tn = d ? (127 - (s + 1)) : (s + 1);
#pragma unroll
      for (int g = 0; g < 4; ++g)
#pragma unroll
        for (int r = 0; r < 4; ++r)
          xv[g][r] = xg[((size_t)(m0 + lk * 4 + r) * 128 + tn) * 2048 + d * 1024 + g * 256 + j];
    }
  }
}

// ---------------------------------------------------------------------------
// attn scores via MFMA: sc[m] = w2 . tanh(W1 @ rnn[m] + b1)
// ---------------------------------------------------------------------------
__global__ __launch_bounds__(256)
void k_attn(const float* __restrict__ rnn, const u16* __restrict__ W1bf,
            const float* __restrict__ b1, const float* __restrict__ w2,
            float* __restrict__ sc) {
  __shared__ __align__(16) u16 sx[32 * 520];
  __shared__ float sred[32];
  int tid = threadIdx.x;
  int rowbase = blockIdx.x * 32;
  for (int idx = tid; idx < 4096; idx += 256) {
    int r = idx >> 7, k4 = idx & 127;
    float4 v = *(const float4*)(rnn + (size_t)(rowbase + r) * 512 + k4 * 4);
    u32* p = (u32*)(sx + r * 520 + k4 * 4);
    p[0] = (u32)f2bf(v.x) | ((u32)f2bf(v.y) << 16);
    p[1] = (u32)f2bf(v.z) | ((u32)f2bf(v.w) << 16);
  }
  if (tid < 32) sred[tid] = 0.f;
  __syncthreads();
  int w = tid >> 6, lane = tid & 63;
  int msub = w >> 1, nhalf = w & 1;
  int mbase = msub * 16;
  float psum[4] = {0.f, 0.f, 0.f, 0.f};
  for (int ng = 0; ng < 4; ++ng) {
    f32x4 acc[4];
#pragma unroll
    for (int i = 0; i < 4; ++i) acc[i] = f32x4{0.f, 0.f, 0.f, 0.f};
    for (int kt = 0; kt < 16; ++kt) {
      short8 a = *(const short8*)(sx + (mbase + (lane & 15)) * 520 + kt * 32 + (lane >> 4) * 8);
#pragma unroll
      for (int nt = 0; nt < 4; ++nt) {
        int nrow = nhalf * 256 + ng * 64 + nt * 16 + (lane & 15);
        short8 b = *(const short8*)(W1bf + (size_t)nrow * 512 + kt * 32 + (lane >> 4) * 8);
        acc[nt] = __builtin_amdgcn_mfma_f32_16x16x32_bf16(a, b, acc[nt], 0, 0, 0);
      }
    }
#pragma unroll
    for (int nt = 0; nt < 4; ++nt) {
      int n = nhalf * 256 + ng * 64 + nt * 16 + (lane & 15);
      float wn = w2[n], bn = b1[n];
#pragma unroll
      for (int r = 0; r < 4; ++r) psum[r] += wn * tanhf(acc[nt][r] + bn);
    }
  }
#pragma unroll
  for (int off = 8; off >= 1; off >>= 1)
#pragma unroll
    for (int r = 0; r < 4; ++r) psum[r] += __shfl_xor(psum[r], off);
  if ((lane & 15) == 0) {
#pragma unroll
    for (int r = 0; r < 4; ++r)
      atomicAdd(&sred[msub * 16 + (lane >> 4) * 4 + r], psum[r]);
  }
  __syncthreads();
  if (tid < 32) sc[rowbase + tid] = sred[tid];
}

// ---------------------------------------------------------------------------
// Causal softmax + weighted sum as prefix scan. grid (64 b, 4 hchunk) x 128.
// ---------------------------------------------------------------------------
__global__ __launch_bounds__(128)
void k_ctx(const float* __restrict__ sc, const float* __restrict__ rnn,
           const int* __restrict__ lens, float* __restrict__ ctx) {
  int b = blockIdx.x;
  int h = blockIdx.y * 128 + threadIdx.x;
  __shared__ float ex[T];
  ex[threadIdx.x] = expf(sc[b * T + threadIdx.x]);
  __syncthreads();
  int len = lens[b];
  float acc = 0.f, den = 0.f;
  for (int t = 0; t < T; ++t) {
    float wv = ex[t];
    den += wv;
    acc += wv * rnn[((size_t)b * T + t) * 512 + h];
    ctx[((size_t)b * T + t) * 512 + h] = (t < len) ? (acc / den) : 0.f;
  }
}

// ---------------------------------------------------------------------------
// MFMA MLP stage on a 32-row bf16 LDS tile
// ---------------------------------------------------------------------------
template <int NT, int KT, bool RELU>
__device__ __forceinline__ void stage_mfma(const u16* __restrict__ Wbf,
                                           const float* __restrict__ bias,
                                           const u16* A, int lda,
                                           u16* O, int ldo, int nofs,
                                           int lane, int msub, int nhalf) {
  f32x4 acc[NT];
#pragma unroll
  for (int i = 0; i < NT; ++i) acc[i] = f32x4{0.f, 0.f, 0.f, 0.f};
  int mbase = msub * 16;
  int nb0 = nhalf * (NT * 16);
#pragma unroll
  for (int kt = 0; kt < KT; ++kt) {
    short8 a = *(const short8*)(A + (mbase + (lane & 15)) * lda + kt * 32 + (lane >> 4) * 8);
#pragma unroll
    for (int nt = 0; nt < NT; ++nt) {
      short8 b = *(const short8*)(Wbf + (size_t)(nb0 + nt * 16 + (lane & 15)) * (KT * 32) +
                                  kt * 32 + (lane >> 4) * 8);
      acc[nt] = __builtin_amdgcn_mfma_f32_16x16x32_bf16(a, b, acc[nt], 0, 0, 0);
    }
  }
  int mr = mbase + (lane >> 4) * 4;
#pragma unroll
  for (int nt = 0; nt < NT; ++nt) {
    int nl = nb0 + nt * 16 + (lane & 15);
    float bv = bias[nl];
#pragma unroll
    for (int r = 0; r < 4; ++r) {
      float v = acc[nt][r] + bv;
      if (RELU) v = fmaxf(v, 0.f);
      O[(mr + r) * ldo + nofs + nl] = f2bf(v);
    }
  }
}

// ---------------------------------------------------------------------------
// Fused sample branch, MFMA everywhere. 32 rows/block, 4096 blocks.
// ---------------------------------------------------------------------------
__global__ __launch_bounds__(256)
void k_sample(const float* __restrict__ ctx, const float* __restrict__ d2v,
              const float* __restrict__ user_table, const float* __restrict__ art_table,
              const int* __restrict__ user_ids, const int* __restrict__ sample_ids,
              const u16* __restrict__ wbf,
              const float* __restrict__ em_b1, const float* __restrict__ em_b2,
              const float* __restrict__ mlp_b,
              const float* __restrict__ lm_b1, const float* __restrict__ lm_b2,
              const float* __restrict__ lm_b3,
              const float* __restrict__ lm_W4, const float* __restrict__ lm_b4,
              float* __restrict__ out) {
  __shared__ __align__(16) u16 bufA[32 * 520];
  __shared__ __align__(16) u16 bufB[32 * 264];
  __shared__ __align__(16) u16 bufC[32 * 136];
  int tid = threadIdx.x, lane = tid & 63, w = tid >> 6;
  int msub = w >> 1, nhalf = w & 1;
  int rowbase = blockIdx.x * 32;

  for (int idx = tid; idx < 1024; idx += 256) {
    int r = idx >> 5, k4 = idx & 31;
    int m = rowbase + r;
    int sid = sample_ids[m];
    int uid = user_ids[m >> 11];
    float4 u = *(const float4*)(user_table + (size_t)uid * 128 + k4 * 4);
    float4 a = *(const float4*)(art_table + (size_t)sid * 128 + k4 * 4);
    u32* p = (u32*)(bufA + r * 520 + k4 * 4);
    p[0] = (u32)f2bf(u.x * a.x) | ((u32)f2bf(u.y * a.y) << 16);
    p[1] = (u32)f2bf(u.z * a.z) | ((u32)f2bf(u.w * a.w) << 16);
  }
  __syncthreads();
  stage_mfma<4, 4, true>(wbf + O_EM1, em_b1, bufA, 520, bufB, 264, 0, lane, msub, nhalf);
  __syncthreads();
  stage_mfma<2, 4, true>(wbf + O_EM2, em_b2, bufB, 264, bufC, 136, 0, lane, msub, nhalf);
  for (int idx = tid; idx < 4096; idx += 256) {
    int r = idx >> 7, k4 = idx & 127;
    int m = rowbase + r;
    int bt = m >> 4;
    float4 cx = *(const float4*)(ctx + (size_t)bt * 512 + k4 * 4);
    float4 dv = *(const float4*)(d2v + (size_t)m * 512 + k4 * 4);
    u32* p = (u32*)(bufA + r * 520 + k4 * 4);
    p[0] = (u32)f2bf(cx.x * dv.x) | ((u32)f2bf(cx.y * dv.y) << 16);
    p[1] = (u32)f2bf(cx.z * dv.z) | ((u32)f2bf(cx.w * dv.w) << 16);
  }
  __syncthreads();
  stage_mfma<2, 16, false>(wbf + O_MLP, mlp_b, bufA, 520, bufC, 136, 64, lane, msub, nhalf);
  __syncthreads();
  stage_mfma<8, 4, true>(wbf + O_LW1, lm_b1, bufC, 136, bufB, 264, 0, lane, msub, nhalf);
  __syncthreads();
  stage_mfma<4, 8, true>(wbf + O_LW2, lm_b2, bufB, 264, bufA, 520, 0, lane, msub, nhalf);
  __syncthreads();
  stage_mfma<2, 4, true>(wbf + O_LW3, lm_b3, bufA, 520, bufC, 136, 0, lane, msub, nhalf);
  __syncthreads();

  if (tid < 32) {
    float acc = lm_b4[0];
#pragma unroll
    for (int k = 0; k < 64; ++k) acc += bf2f(bufC[tid * 136 + k]) * lm_W4[k];
    out[rowbase + tid] = 1.f / (1.f + expf(-acc));
  }
}

}  // namespace

extern "C" void kernel_launch(void* const* d_in, const int* in_sizes, int n_in,
                              void* d_out, int out_size, void* d_ws, size_t ws_size,
                              hipStream_t stream) {
  const float* x1   = (const float*)d_in[0];
  const float* d2v  = (const float*)d_in[1];
  const float* Wih  = (const float*)d_in[2];
  const float* Whh  = (const float*)d_in[3];
  const float* bih  = (const float*)d_in[4];
  const float* bhh  = (const float*)d_in[5];
  const float* aW1  = (const float*)d_in[6];
  const float* ab1  = (const float*)d_in[7];
  const float* aw2  = (const float*)d_in[8];
  const float* mlpW = (const float*)d_in[9];
  const float* mlpb = (const float*)d_in[10];
  const float* utab = (const float*)d_in[11];
  const float* atab = (const float*)d_in[12];
  const float* emW1 = (const float*)d_in[13];
  const float* emb1 = (const float*)d_in[14];
  const float* emW2 = (const float*)d_in[15];
  const float* emb2 = (const float*)d_in[16];
  const float* lmW1 = (const float*)d_in[17];
  const float* lmb1 = (const float*)d_in[18];
  const float* lmW2 = (const float*)d_in[19];
  const float* lmb2 = (const float*)d_in[20];
  const float* lmW3 = (const float*)d_in[21];
  const float* lmb3 = (const float*)d_in[22];
  const float* lmW4 = (const float*)d_in[23];
  const float* lmb4 = (const float*)d_in[24];
  const int* lens   = (const int*)d_in[27];
  const int* uids   = (const int*)d_in[28];
  const int* sids   = (const int*)d_in[29];
  float* out = (float*)d_out;

  float* ws = (float*)d_ws;
  // float-unit offsets
  u32* FLG = (u32*)ws;                                 // 128 u32   [0, 128)
  u16* HG  = (u16*)(ws + 128);                         // 65536 u16 [128, 32896)
  float* SC  = ws + 32896;                             // 8192
  u16* WBF = (u16*)(ws + 41088);                       // 2,490,368 u16
  float* XG  = ws + 1286272;                           // 16,777,216
  float* R0  = ws + 18063488;                          // 4,194,304
  float* R1  = ws + 22257792;                          // 4,194,304
  float* CTX = ws + 26452096;                          // 4,194,304

  hipMemsetAsync(FLG, 0, 512, stream);
  k_prep<<<(N_WBF + 255) / 256, 256, 0, stream>>>(Wih, aW1, emW1, emW2, mlpW,
                                                  lmW1, lmW2, lmW3, WBF);
  k_xg_mfma<<<dim3(256, 8), 256, 0, stream>>>(x1, WBF + O_WIH, bih, bhh, XG);
  k_lstm4<<<32, 256, 0, stream>>>(XG, Whh, lens, R0, HG, FLG, 0);
  k_xg_mfma<<<dim3(256, 8), 256, 0, stream>>>(R0, WBF + O_WIH + 1048576,
                                              bih + 2048, bhh + 2048, XG);
  k_lstm4<<<32, 256, 0, stream>>>(XG, Whh, lens, R1, HG, FLG, 1);
  k_attn<<<256, 256, 0, stream>>>(R1, WBF + O_AW1, ab1, aw2, SC);
  k_ctx<<<dim3(64, 4), 128, 0, stream>>>(SC, R1, lens, CTX);
  k_sample<<<4096, 256, 0, stream>>>(CTX, d2v, utab, atab, uids, sids, WBF,
                                     emb1, emb2, mlpb, lmb1, lmb2, lmb3,
                                     lmW4, lmb4, out);
}